// Round 14
// baseline (608.652 us; speedup 1.0000x reference)
//
#include <hip/hip_runtime.h>
#include <math.h>

#define L_SEQ 512
#define BATCH 128
#define DIN   128
#define HID   512
#define NOUT  5
#define NSTR  1536   // full C row stride (u0|u1|u2 panels)

typedef unsigned short u16;
typedef unsigned int   u32;
typedef __attribute__((ext_vector_type(8))) short short8;
typedef __attribute__((ext_vector_type(4))) float f32x4;

// ---------------------------------------------------------------------------
// bf16 split helpers (RNE).
// ---------------------------------------------------------------------------
__device__ __forceinline__ u16 f2bf(float x) {
  u32 u = __float_as_uint(x);
  return (u16)((u + 0x7fffu + ((u >> 16) & 1u)) >> 16);
}
__device__ __forceinline__ float bf2f(u16 s) {
  return __uint_as_float(((u32)s) << 16);
}
__device__ __forceinline__ void gload16(const void* g, void* l) {
  __builtin_amdgcn_global_load_lds(
      (const __attribute__((address_space(1))) u32*)g,
      (__attribute__((address_space(3))) u32*)l, 16, 0, 0);
}
__device__ __forceinline__ float sig(float x) { return 1.f / (1.f + __expf(-x)); }

// ---------------------------------------------------------------------------
// Rider: layer-1 scan (u0/u1 only, no lastT) vectorized 4 chains/thread.
// 64 blocks x 256 threads x 4 = 65536 chains. Reads U (stride S), updates c1.
// ---------------------------------------------------------------------------
__device__ void scan1_vec4(int idx, const float* __restrict__ U, int S,
                           const float* __restrict__ v, const float* __restrict__ bias,
                           float* __restrict__ c1, int Tc, int init) {
  const int j4 = idx * 4;
  const int b = j4 >> 9, h = j4 & (HID - 1);
  const float4 vf = *(const float4*)(v + h);
  const float4 bf = *(const float4*)(bias + h);
  const float* p = U + (size_t)b * S + h;
  const size_t sT = (size_t)BATCH * S;

  float4 c;
  if (init) { c.x = c.y = c.z = c.w = 0.f; } else { c = *(const float4*)(c1 + j4); }

  float4 u0g[4], u1g[4];
#pragma unroll
  for (int q = 0; q < 4; ++q) {
    u0g[q] = *(const float4*)(p + q * sT);
    u1g[q] = *(const float4*)(p + q * sT + HID);
  }
  const int NG = Tc >> 2;
  for (int g = 0; g < NG; ++g) {
    float4 n0[4], n1[4];
    const bool has = (g + 1 < NG);
    if (has) {
      const float* pn = p + 4 * sT;
#pragma unroll
      for (int q = 0; q < 4; ++q) {
        n0[q] = *(const float4*)(pn + q * sT);
        n1[q] = *(const float4*)(pn + q * sT + HID);
      }
    }
#pragma unroll
    for (int q = 0; q < 4; ++q) {
      float4 f;
      f.x = sig(u1g[q].x + vf.x * c.x + bf.x);
      f.y = sig(u1g[q].y + vf.y * c.y + bf.y);
      f.z = sig(u1g[q].z + vf.z * c.z + bf.z);
      f.w = sig(u1g[q].w + vf.w * c.w + bf.w);
      c.x = f.x * c.x + (1.f - f.x) * u0g[q].x;
      c.y = f.y * c.y + (1.f - f.y) * u0g[q].y;
      c.z = f.z * c.z + (1.f - f.z) * u0g[q].z;
      c.w = f.w * c.w + (1.f - f.w) * u0g[q].w;
    }
    p += 4 * sT;
    if (has) {
#pragma unroll
      for (int q = 0; q < 4; ++q) { u0g[q] = n0[q]; u1g[q] = n1[q]; }
    }
  }
  *(float4*)(c1 + j4) = c;
}

// ---------------------------------------------------------------------------
// R3-verified split-bf16 MFMA GEMM body (unchanged since R13 except runtime
// C stride). Triple-role dispatch: [nrider scan1 blocks][nb0 g0][nb1 g1].
// Riders first: bounded slot-steal; they finish early and free slots.
// ---------------------------------------------------------------------------
struct GArgs {
  const u16* Ah; const u16* Al;   // A hi/lo  [M][K]
  const u16* Bh; const u16* Bl;   // B^T hi/lo [N][K]
  float* C;                       // [M][Cs]
  int K;                          // 512 or 128
  int NBX;                        // 128-col panels (4/8/12)
  int Cs;                         // C row stride (1024 or 1536)
};

__global__ __launch_bounds__(256, 4)
void gemm_tri(GArgs g0, int nb0, GArgs g1, int nb1,
              const float* sU, int sS, const float* sv, const float* sb,
              float* sc1, int sTc, int sInit, int nrider) {
  if ((int)blockIdx.x < nrider) {
    scan1_vec4((int)blockIdx.x * 256 + threadIdx.x, sU, sS, sv, sb, sc1, sTc, sInit);
    return;
  }
  const int bxg = (int)blockIdx.x - nrider;
  const bool first = bxg < nb0;
  const GArgs g = first ? g0 : g1;
  int bid = first ? bxg : bxg - nb0;
  const int nsub = first ? nb0 : nb1;
  if ((nsub & 7) == 0) {          // bijective XCD swizzle per sub-grid
    const int cpx = nsub >> 3;
    bid = (bid & 7) * cpx + (bid >> 3);
  }
  const int K = g.K;

  __shared__ u16 sAh[4096], sAl[4096], sBh[4096], sBl[4096];

  const int bx = bid % g.NBX;
  const int by = bid / g.NBX;
  const int tid = threadIdx.x;
  const int wid = tid >> 6, lane = tid & 63;

  const int srow = tid >> 2;
  const int sw = (tid & 3) ^ ((srow >> 1) & 3);   // swizzled 16B slot
  const size_t aoff0 = (size_t)(by * 128 + srow) * K + sw * 8;
  const size_t aoff1 = aoff0 + (size_t)64 * K;
  const size_t boff0 = (size_t)(bx * 128 + srow) * K + sw * 8;
  const size_t boff1 = boff0 + (size_t)64 * K;
  const int d0 = wid * 512;
  const int d1 = 2048 + wid * 512;

  const int wm = wid >> 1, wn = wid & 1;
  const int frow = lane & 15, fsl = lane >> 4;
  int offA[4], offB[4];
#pragma unroll
  for (int i = 0; i < 4; ++i) {
    const int ra = wm * 64 + i * 16 + frow;
    offA[i] = ra * 32 + ((fsl ^ ((ra >> 1) & 3)) * 8);
    const int rb = wn * 64 + i * 16 + frow;
    offB[i] = rb * 32 + ((fsl ^ ((rb >> 1) & 3)) * 8);
  }

  f32x4 acc[4][4];
#pragma unroll
  for (int i = 0; i < 4; ++i)
#pragma unroll
    for (int j = 0; j < 4; ++j)
#pragma unroll
      for (int q = 0; q < 4; ++q) acc[i][j][q] = 0.f;

  for (int k0 = 0; k0 < K; k0 += 32) {
    __syncthreads();
    gload16(g.Ah + aoff0 + k0, &sAh[d0]);
    gload16(g.Ah + aoff1 + k0, &sAh[d1]);
    gload16(g.Al + aoff0 + k0, &sAl[d0]);
    gload16(g.Al + aoff1 + k0, &sAl[d1]);
    gload16(g.Bh + boff0 + k0, &sBh[d0]);
    gload16(g.Bh + boff1 + k0, &sBh[d1]);
    gload16(g.Bl + boff0 + k0, &sBl[d0]);
    gload16(g.Bl + boff1 + k0, &sBl[d1]);
    __syncthreads();

    short8 bh[4], bl[4];
#pragma unroll
    for (int j = 0; j < 4; ++j) {
      bh[j] = *(const short8*)&sBh[offB[j]];
      bl[j] = *(const short8*)&sBl[offB[j]];
    }
#pragma unroll
    for (int i = 0; i < 4; ++i) {
      const short8 ah = *(const short8*)&sAh[offA[i]];
      const short8 al = *(const short8*)&sAl[offA[i]];
#pragma unroll
      for (int j = 0; j < 4; ++j) {
        acc[i][j] = __builtin_amdgcn_mfma_f32_16x16x32_bf16(ah, bh[j], acc[i][j], 0, 0, 0);
        acc[i][j] = __builtin_amdgcn_mfma_f32_16x16x32_bf16(ah, bl[j], acc[i][j], 0, 0, 0);
        acc[i][j] = __builtin_amdgcn_mfma_f32_16x16x32_bf16(al, bh[j], acc[i][j], 0, 0, 0);
      }
    }
  }

  // epilogue: C/D layout col=lane&15, row=(lane>>4)*4+q  [R3-verified]
  const int crow0 = by * 128 + wm * 64 + (lane >> 4) * 4;
  const int ccol0 = bx * 128 + wn * 64 + (lane & 15);
#pragma unroll
  for (int i = 0; i < 4; ++i)
#pragma unroll
    for (int j = 0; j < 4; ++j) {
      float* cp = g.C + (size_t)(crow0 + i * 16) * g.Cs + ccol0 + j * 16;
#pragma unroll
      for (int q = 0; q < 4; ++q) cp[(size_t)q * g.Cs] = acc[i][j][q];
    }
}

// ---------------------------------------------------------------------------
// one-time input conversions
// ---------------------------------------------------------------------------
__global__ __launch_bounds__(256)
void split4_f32(const float* __restrict__ in, u16* __restrict__ hi,
                u16* __restrict__ lo, int n4) {
  const int i = blockIdx.x * 256 + threadIdx.x;
  if (i >= n4) return;
  const float4 v = ((const float4*)in)[i];
  u16 h0 = f2bf(v.x), h1 = f2bf(v.y), h2 = f2bf(v.z), h3 = f2bf(v.w);
  u16 l0 = f2bf(v.x - bf2f(h0)), l1 = f2bf(v.y - bf2f(h1));
  u16 l2 = f2bf(v.z - bf2f(h2)), l3 = f2bf(v.w - bf2f(h3));
  uint2 hp, lp;
  hp.x = (u32)h0 | ((u32)h1 << 16); hp.y = (u32)h2 | ((u32)h3 << 16);
  lp.x = (u32)l0 | ((u32)l1 << 16); lp.y = (u32)l2 | ((u32)l3 << 16);
  ((uint2*)hi)[i] = hp;
  ((uint2*)lo)[i] = lp;
}

__global__ __launch_bounds__(256)
void split_w_t(const float* __restrict__ W, u16* __restrict__ Th,
               u16* __restrict__ Tl, int K, int N) {
  const int idx = blockIdx.x * 256 + threadIdx.x;
  if (idx >= K * N) return;
  const int k = idx / N, n = idx - k * N;
  const float x = W[idx];
  const u16 h = f2bf(x);
  Th[(size_t)n * K + k] = h;
  Tl[(size_t)n * K + k] = f2bf(x - bf2f(h));
}

// ---------------------------------------------------------------------------
// Layer-0 scan (reads full-stride U0, emits h1 hi/lo bf16), group-8 pipeline.
// ---------------------------------------------------------------------------
__global__ __launch_bounds__(256)
void sru_scan0(const float* __restrict__ U, const float* __restrict__ v,
               const float* __restrict__ bias, u16* __restrict__ h1h,
               u16* __restrict__ h1l, float* __restrict__ cstate, int Tc, int init) {
  const int j = blockIdx.x * 256 + threadIdx.x;
  const int b = j >> 9, h = j & (HID - 1);
  const float vf = v[h], vr = v[HID + h];
  const float bf = bias[h], br = bias[HID + h];

  const float* p = U + (size_t)b * NSTR + h;
  const size_t sT = (size_t)BATCH * NSTR;
  u16* ph = h1h + (size_t)b * HID + h;
  u16* pl = h1l + (size_t)b * HID + h;
  const size_t sH = (size_t)BATCH * HID;

  float c = init ? 0.f : cstate[j];
  float cu[24];
#pragma unroll
  for (int q = 0; q < 8; ++q) {
    cu[3 * q + 0] = p[q * sT];
    cu[3 * q + 1] = p[q * sT + HID];
    cu[3 * q + 2] = p[q * sT + 2 * HID];
  }
  const int NG = Tc >> 3;
  for (int g = 0; g < NG; ++g) {
    float nx[24];
    const bool has = (g + 1 < NG);
    if (has) {
      const float* pn = p + 8 * sT;
#pragma unroll
      for (int q = 0; q < 8; ++q) {
        nx[3 * q + 0] = pn[q * sT];
        nx[3 * q + 1] = pn[q * sT + HID];
        nx[3 * q + 2] = pn[q * sT + 2 * HID];
      }
    }
#pragma unroll
    for (int q = 0; q < 8; ++q) {
      const float u0 = cu[3 * q], u1 = cu[3 * q + 1], u2 = cu[3 * q + 2];
      const float f = sig(u1 + vf * c + bf);
      const float r = sig(u2 + vr * c + br);
      c = f * c + (1.f - f) * u0;
      const float hv = r * c;
      const u16 hh = f2bf(hv);
      ph[(size_t)(g * 8 + q) * sH] = hh;
      pl[(size_t)(g * 8 + q) * sH] = f2bf(hv - bf2f(hh));
    }
    p += 8 * sT;
    if (has) {
#pragma unroll
      for (int i = 0; i < 24; ++i) cu[i] = nx[i];
    }
  }
  cstate[j] = c;
}

// ---------------------------------------------------------------------------
// Standalone layer-1 scan for the FINAL chunk (full-stride U, u2/lastT path).
// ---------------------------------------------------------------------------
__global__ __launch_bounds__(256)
void sru_scan1(const float* __restrict__ U, const float* __restrict__ v,
               const float* __restrict__ bias, float* __restrict__ cstate,
               float* __restrict__ hlast, int Tc, int lastT, int init) {
  const int j = blockIdx.x * 256 + threadIdx.x;
  const int b = j >> 9, h = j & (HID - 1);
  const float vf = v[h], vr = v[HID + h];
  const float bf = bias[h], br = bias[HID + h];

  const float* p = U + (size_t)b * NSTR + h;
  const size_t sT = (size_t)BATCH * NSTR;

  float c = init ? 0.f : cstate[j];
  float cu[16];
#pragma unroll
  for (int q = 0; q < 8; ++q) {
    cu[2 * q + 0] = p[q * sT];
    cu[2 * q + 1] = p[q * sT + HID];
  }
  const int NG = Tc >> 3;
  for (int g = 0; g < NG; ++g) {
    float nx[16];
    const bool has = (g + 1 < NG);
    if (has) {
      const float* pn = p + 8 * sT;
#pragma unroll
      for (int q = 0; q < 8; ++q) {
        nx[2 * q + 0] = pn[q * sT];
        nx[2 * q + 1] = pn[q * sT + HID];
      }
    }
#pragma unroll
    for (int q = 0; q < 8; ++q) {
      const float u0 = cu[2 * q], u1 = cu[2 * q + 1];
      const float f = sig(u1 + vf * c + bf);
      const float cn = f * c + (1.f - f) * u0;
      if (g * 8 + q == lastT) {            // uniform; true once per sequence
        const float u2 = p[q * sT + 2 * HID];
        const float r = sig(u2 + vr * c + br);
        hlast[j] = r * cn;
      }
      c = cn;
    }
    p += 8 * sT;
    if (has) {
#pragma unroll
      for (int i = 0; i < 16; ++i) cu[i] = nx[i];
    }
  }
  cstate[j] = c;
}

// ---------------------------------------------------------------------------
__global__ __launch_bounds__(256)
void fc_head(const float* __restrict__ h, const float* __restrict__ w,
             const float* __restrict__ bias, float* __restrict__ out) {
  const int gid = blockIdx.x * 256 + threadIdx.x;
  const int wv = gid >> 6, lane = threadIdx.x & 63;
  if (wv >= BATCH * NOUT) return;
  const int b = wv / NOUT, o = wv % NOUT;
  float s = 0.f;
#pragma unroll
  for (int k = lane; k < HID; k += 64)
    s += h[(size_t)b * HID + k] * w[(size_t)o * HID + k];
#pragma unroll
  for (int off = 32; off > 0; off >>= 1) s += __shfl_down(s, off);
  if (lane == 0) out[(size_t)b * NOUT + o] = s + bias[o];
}

// ---------------------------------------------------------------------------
extern "C" void kernel_launch(void* const* d_in, const int* in_sizes, int n_in,
                              void* d_out, int out_size, void* d_ws, size_t ws_size,
                              hipStream_t stream) {
  const float* x   = (const float*)d_in[0];
  const float* W0  = (const float*)d_in[1];
  const float* v0  = (const float*)d_in[2];
  const float* b0  = (const float*)d_in[3];
  const float* W1  = (const float*)d_in[4];
  const float* v1  = (const float*)d_in[5];
  const float* b1  = (const float*)d_in[6];
  const float* fcw = (const float*)d_in[7];
  const float* fcb = (const float*)d_in[8];
  float* out = (float*)d_out;

  const size_t nX  = (size_t)L_SEQ * BATCH * DIN;   // 8.39M
  const size_t nW0 = (size_t)DIN * NSTR;
  const size_t nW1 = (size_t)HID * NSTR;

  // footprint(Tc) = U0 full + 2x U1 (stride 1024) f32 + states + u16 arrays.
  // Tc=64 -> ~205 MB (< 238 MB proven in R13).
  int Tc = 64;
  for (;;) {
    size_t f32e = (size_t)Tc * BATCH * NSTR + 2 * (size_t)Tc * BATCH * 1024 +
                  3 * (size_t)BATCH * HID;
    size_t u16e = 2 * nX + 4 * (size_t)Tc * BATCH * HID + 2 * nW0 + 2 * nW1;
    if (f32e * 4 + u16e * 2 + 1024 <= ws_size || Tc <= 8) break;
    Tc >>= 1;
  }
  const int NC = L_SEQ / Tc;
  const int Mc = Tc * BATCH;

  float* U0    = (float*)d_ws;                      // [Mc][1536] (layer0 U; last-chunk layer1 U)
  float* U1a   = U0  + (size_t)Mc * NSTR;           // [Mc][1024] ping (u0|u1)
  float* U1b   = U1a + (size_t)Mc * 1024;           // pong
  float* c0    = U1b + (size_t)Mc * 1024;
  float* c1    = c0 + (size_t)BATCH * HID;
  float* h2    = c1 + (size_t)BATCH * HID;
  u16* xs_h    = (u16*)(h2 + (size_t)BATCH * HID);
  u16* xs_l    = xs_h + nX;
  u16* h1h_a   = xs_l + nX;                         // [Mc][512] ping
  u16* h1l_a   = h1h_a + (size_t)Mc * HID;
  u16* h1h_b   = h1l_a + (size_t)Mc * HID;          // pong
  u16* h1l_b   = h1h_b + (size_t)Mc * HID;
  u16* w0t_h   = h1l_b + (size_t)Mc * HID;
  u16* w0t_l   = w0t_h + nW0;
  u16* w1t_h   = w0t_l + nW0;
  u16* w1t_l   = w1t_h + nW1;

  float* U1[2] = {U1a, U1b};
  u16* h1h[2]  = {h1h_a, h1h_b};
  u16* h1l[2]  = {h1l_a, h1l_b};

  const int rows   = Mc / 128;                      // 64 at Tc=64
  const int fcGrid = (BATCH * NOUT * 64 + 255) / 256;
  const int NRIDER = (BATCH * HID) / (256 * 4);     // 64 blocks, 4 chains/thread

  // one-time conversions
  split4_f32<<<(int)(nX / 4 + 255) / 256, 256, 0, stream>>>(x, xs_h, xs_l, (int)(nX / 4));
  split_w_t<<<(int)(nW0 + 255) / 256, 256, 0, stream>>>(W0, w0t_h, w0t_l, DIN, NSTR);
  split_w_t<<<(int)(nW1 + 255) / 256, 256, 0, stream>>>(W1, w1t_h, w1t_l, HID, NSTR);

  // prologue: GEMM0(0) -> U0; scan0(0)
  {
    GArgs ga = {xs_h, xs_l, w0t_h, w0t_l, U0, DIN, 12, NSTR};
    gemm_tri<<<rows * 12, 256, 0, stream>>>(ga, rows * 12, ga, 0,
                                            nullptr, 0, nullptr, nullptr,
                                            nullptr, 0, 0, 0);
    sru_scan0<<<(BATCH * HID) / 256, 256, 0, stream>>>(U0, v0, b0,
                                                       h1h[0], h1l[0], c0, Tc, 1);
  }

  for (int ch = 0; ch < NC; ++ch) {
    const bool last = (ch == NC - 1);
    const int cur = ch & 1, nxt = cur ^ 1;

    // g0: GEMM1(ch). Non-last: u0|u1 panels (NBX=8) into stride-1024 U1[cur].
    //     Last: full 12 panels into the (now dead) full-stride U0.
    GArgs g1 = {h1h[cur], h1l[cur], w1t_h, w1t_l,
                last ? U0 : U1[cur], HID, last ? 12 : 8, last ? NSTR : 1024};
    const int nb0 = rows * (last ? 12 : 8);
    // g1: GEMM0(ch+1) -> U0 (safe: scan0(ch) consumed U0 in the previous dispatch)
    GArgs g0n = g1;
    int nb1 = 0;
    if (!last) {
      const size_t xoff = (size_t)(ch + 1) * Mc * DIN;
      g0n = GArgs{xs_h + xoff, xs_l + xoff, w0t_h, w0t_l, U0, DIN, 12, NSTR};
      nb1 = rows * 12;
    }
    // rider: scan1(ch-1) over U1[(ch-1)&1] (stride 1024), updates c1 only
    const int nr = (ch > 0) ? NRIDER : 0;
    gemm_tri<<<nr + nb0 + nb1, 256, 0, stream>>>(
        g1, nb0, g0n, nb1,
        (ch > 0) ? U1[(ch - 1) & 1] : nullptr, 1024, v1, b1, c1, Tc,
        (ch == 1) ? 1 : 0, nr);

    if (!last)
      sru_scan0<<<(BATCH * HID) / 256, 256, 0, stream>>>(U0, v0, b0,
                                                         h1h[nxt], h1l[nxt], c0, Tc, 0);
  }
  // final: scan1 over last chunk (full-stride U0, u2/lastT path), writes h2
  sru_scan1<<<(BATCH * HID) / 256, 256, 0, stream>>>(
      U0, v1, b1, c1, h2, Tc, Tc - 1, (NC == 1) ? 1 : 0);
  fc_head<<<fcGrid, 256, 0, stream>>>(h2, fcw, fcb, out);
}